// Round 1
// baseline (608.740 us; speedup 1.0000x reference)
//
#include <hip/hip_runtime.h>

// out[b,c,h,w] = x[b,c, h^3, w^3]  (combined adjacent+interlaced perm = reverse
// each block of 4 on both H and W; 256 % 4 == 0 so no tail handling).
// Flat:  out[e] = in[e ^ 0x303].
// float4: out4[t] = reverse_components(in4[t ^ 0xC0]).
// Both sides coalesced at 16 B/lane; pure HBM-streaming permute.

__global__ __launch_bounds__(256) void dualswitch_kernel(
    const float4* __restrict__ in, float4* __restrict__ out) {
    const int t = blockIdx.x * 256 + threadIdx.x;
    const float4 v = in[t ^ 0xC0];              // h ^= 3 (rows within 4-row group)
    out[t] = make_float4(v.w, v.z, v.y, v.x);   // w ^= 3 (reverse inside float4)
}

extern "C" void kernel_launch(void* const* d_in, const int* in_sizes, int n_in,
                              void* d_out, int out_size, void* d_ws, size_t ws_size,
                              hipStream_t stream) {
    const float4* in = (const float4*)d_in[0];
    float4* out = (float4*)d_out;
    const int total4 = out_size / 4;            // 16*96*256*256/4 = 25165824
    const int blocks = total4 / 256;            // 98304, exact
    dualswitch_kernel<<<blocks, 256, 0, stream>>>(in, out);
}